// Round 12
// baseline (67.760 us; speedup 1.0000x reference)
//
#include <hip/hip_runtime.h>
#include <cstdint>

#define P 7
#define PP 49
#define IMG 64
#define PIX 4096
#define XSTR 72    // LDS row stride: 288B, 16B-aligned rows -> b128 merging
#define XROWS 28   // xs tile rows: x rows q*16-6 .. q*16+21
#define MROWS 22   // ms tile rows: maps1 rows q*16-3 .. q*16+18

// fence: only ALU/VALU may cross -> DS reads stay pinned to their region
#define FENCE __builtin_amdgcn_sched_barrier(0x3);
#define NOPF

// ---- two 10-float window row sets (named scalars; alternate per row) ----
#define DECLRQ \
    float r0,r1,r2,r3,r4,r5,r6,r7,r8,r9; \
    float q0,q1,q2,q3,q4,q5,q6,q7,q8,q9;

#define LDR(BP) { const float* _p=(BP); r0=_p[0];r1=_p[1];r2=_p[2];r3=_p[3];r4=_p[4];r5=_p[5];r6=_p[6];r7=_p[7];r8=_p[8];r9=_p[9]; }
#define LDQ(BP) { const float* _p=(BP); q0=_p[0];q1=_p[1];q2=_p[2];q3=_p[3];q4=_p[4];q5=_p[5];q6=_p[6];q7=_p[7];q8=_p[8];q9=_p[9]; }

// per-row sums: px p uses cols p..p+6, j-ascending (bit-identical to r11)
#define SUMR \
    s0+=r0; s1+=r1; s2+=r2; s3+=r3; \
    s0+=r1; s1+=r2; s2+=r3; s3+=r4; \
    s0+=r2; s1+=r3; s2+=r4; s3+=r5; \
    s0+=r3; s1+=r4; s2+=r5; s3+=r6; \
    s0+=r4; s1+=r5; s2+=r6; s3+=r7; \
    s0+=r5; s1+=r6; s2+=r7; s3+=r8; \
    s0+=r6; s1+=r7; s2+=r8; s3+=r9;
#define SUMQ \
    s0+=q0; s1+=q1; s2+=q2; s3+=q3; \
    s0+=q1; s1+=q2; s2+=q3; s3+=q4; \
    s0+=q2; s1+=q3; s2+=q4; s3+=q5; \
    s0+=q3; s1+=q4; s2+=q5; s3+=q6; \
    s0+=q4; s1+=q5; s2+=q6; s3+=q7; \
    s0+=q5; s1+=q6; s2+=q7; s3+=q8; \
    s0+=q6; s1+=q7; s2+=q8; s3+=q9;

// pipelined sum pass: load row i+1 while summing row i (rows ascending)
#define SUMPASS(B) \
    LDR((B)+0*XSTR) FENCE \
    LDQ((B)+1*XSTR) FENCE \
    SUMR FENCE \
    LDR((B)+2*XSTR) FENCE \
    SUMQ FENCE \
    LDQ((B)+3*XSTR) FENCE \
    SUMR FENCE \
    LDR((B)+4*XSTR) FENCE \
    SUMQ FENCE \
    LDQ((B)+5*XSTR) FENCE \
    SUMR FENCE \
    LDR((B)+6*XSTR) FENCE \
    SUMQ FENCE \
    SUMR

// ---- stage 1 taps: weight double-buffer u0/u1, prefetch 1 tap ahead ----
#define S1C(W,RA,RB,RC,RD) \
    a0=fmaf(W,(RA)-mu0,a0); a1=fmaf(W,(RB)-mu1,a1); \
    a2=fmaf(W,(RC)-mu2,a2); a3=fmaf(W,(RD)-mu3,a3);

#define S1ROW_E(i, ROWPF) \
    u1 = w1s[(i)*7+1]; ROWPF S1C(u0, r0,r1,r2,r3) FENCE \
    u0 = w1s[(i)*7+2]; S1C(u1, r1,r2,r3,r4) FENCE \
    u1 = w1s[(i)*7+3]; S1C(u0, r2,r3,r4,r5) FENCE \
    u0 = w1s[(i)*7+4]; S1C(u1, r3,r4,r5,r6) FENCE \
    u1 = w1s[(i)*7+5]; S1C(u0, r4,r5,r6,r7) FENCE \
    u0 = w1s[(i)*7+6]; S1C(u1, r5,r6,r7,r8) FENCE \
    u1 = w1s[(i)*7+7]; S1C(u0, r6,r7,r8,r9) FENCE
#define S1ROW_O(i, ROWPF) \
    u0 = w1s[(i)*7+1]; ROWPF S1C(u1, q0,q1,q2,q3) FENCE \
    u1 = w1s[(i)*7+2]; S1C(u0, q1,q2,q3,q4) FENCE \
    u0 = w1s[(i)*7+3]; S1C(u1, q2,q3,q4,q5) FENCE \
    u1 = w1s[(i)*7+4]; S1C(u0, q3,q4,q5,q6) FENCE \
    u0 = w1s[(i)*7+5]; S1C(u1, q4,q5,q6,q7) FENCE \
    u1 = w1s[(i)*7+6]; S1C(u0, q5,q6,q7,q8) FENCE \
    u0 = w1s[(i)*7+7]; S1C(u1, q6,q7,q8,q9) FENCE

// ---- stage 2 taps: weight double-buffer (wA0,wB0)/(wA1,wB1), 1 ahead ----
#define PF2(T, S) \
    wA##S = *(const float4*)&w2s[(T)*8]; \
    wB##S = *(const float4*)&w2s[(T)*8+4];

// fmaf order identical to r11: filters ascending, pixels a,b,c,d per filter
#define S2C(S, RA,RB,RC,RD) { \
    const float t0=(RA)-mu0, t1=(RB)-mu1, t2=(RC)-mu2, t3=(RD)-mu3; \
    a0=fmaf(wA##S.x,t0,a0); b0=fmaf(wA##S.x,t1,b0); c0=fmaf(wA##S.x,t2,c0); d0=fmaf(wA##S.x,t3,d0); \
    a1=fmaf(wA##S.y,t0,a1); b1=fmaf(wA##S.y,t1,b1); c1=fmaf(wA##S.y,t2,c1); d1=fmaf(wA##S.y,t3,d1); \
    a2=fmaf(wA##S.z,t0,a2); b2=fmaf(wA##S.z,t1,b2); c2=fmaf(wA##S.z,t2,c2); d2=fmaf(wA##S.z,t3,d2); \
    a3=fmaf(wA##S.w,t0,a3); b3=fmaf(wA##S.w,t1,b3); c3=fmaf(wA##S.w,t2,c3); d3=fmaf(wA##S.w,t3,d3); \
    a4=fmaf(wB##S.x,t0,a4); b4=fmaf(wB##S.x,t1,b4); c4=fmaf(wB##S.x,t2,c4); d4=fmaf(wB##S.x,t3,d4); \
    a5=fmaf(wB##S.y,t0,a5); b5=fmaf(wB##S.y,t1,b5); c5=fmaf(wB##S.y,t2,c5); d5=fmaf(wB##S.y,t3,d5); \
    a6=fmaf(wB##S.z,t0,a6); b6=fmaf(wB##S.z,t1,b6); c6=fmaf(wB##S.z,t2,c6); d6=fmaf(wB##S.z,t3,d6); \
    a7=fmaf(wB##S.w,t0,a7); b7=fmaf(wB##S.w,t1,b7); c7=fmaf(wB##S.w,t2,c7); d7=fmaf(wB##S.w,t3,d7); }

#define S2ROW_E(i, ROWPF) \
    PF2((i)*7+1,1) ROWPF S2C(0, r0,r1,r2,r3) FENCE \
    PF2((i)*7+2,0) S2C(1, r1,r2,r3,r4) FENCE \
    PF2((i)*7+3,1) S2C(0, r2,r3,r4,r5) FENCE \
    PF2((i)*7+4,0) S2C(1, r3,r4,r5,r6) FENCE \
    PF2((i)*7+5,1) S2C(0, r4,r5,r6,r7) FENCE \
    PF2((i)*7+6,0) S2C(1, r5,r6,r7,r8) FENCE \
    PF2((i)*7+7,1) S2C(0, r6,r7,r8,r9) FENCE
#define S2ROW_O(i, ROWPF) \
    PF2((i)*7+1,0) ROWPF S2C(1, q0,q1,q2,q3) FENCE \
    PF2((i)*7+2,1) S2C(0, q1,q2,q3,q4) FENCE \
    PF2((i)*7+3,0) S2C(1, q2,q3,q4,q5) FENCE \
    PF2((i)*7+4,1) S2C(0, q3,q4,q5,q6) FENCE \
    PF2((i)*7+5,0) S2C(1, q4,q5,q6,q7) FENCE \
    PF2((i)*7+6,1) S2C(0, q5,q6,q7,q8) FENCE \
    PF2((i)*7+7,0) S2C(1, q6,q7,q8,q9) FENCE

// ---------------------------------------------------------------------------
// One block per (channel, row-quarter): 2048 blocks x 256 threads.
// r11 structure + one-ahead software pipelining of ALL DS loads (weights and
// window rows) inside the fence regions: each tap's operands were loaded a
// full region (~36 VALU) earlier, so the lgkm wait lands after useful work.
// Arithmetic sequence unchanged -> bit-identical (absmax 0 in r11).
// ---------------------------------------------------------------------------
__global__ __launch_bounds__(256, 4) void stage_kernel(
    const float* __restrict__ x,    // [64][64][64]
    const float* __restrict__ W1,   // [49][8]
    const float* __restrict__ W2,   // [49][8]
    uint8_t* __restrict__ codes)    // [512][4096]
{
    __shared__ __align__(16) float xs[XROWS * XSTR];
    __shared__ __align__(16) float ms[MROWS * XSTR];
    __shared__ float w1s[PP + 7];            // +pad: pipeline prefetch overrun
    __shared__ __align__(16) float w2s[PP * 8 + 8];  // +pad

    const int b    = blockIdx.x;
    const int ch   = b >> 2;
    const int q16  = (b & 3) * 16;
    const int l    = ch >> 6;
    const int img  = ch & 63;
    const int tid  = threadIdx.x;

    // stage weights into LDS (all threads cover all elements)
    if (tid < PP) w1s[tid] = W1[tid * 8 + l];
    if (tid >= PP && tid < PP + 7) w1s[tid] = 0.f;   // pad
    #pragma unroll 1
    for (int i = tid; i < PP * 8 + 8; i += 256) w2s[i] = (i < PP * 8) ? W2[i] : 0.f;

    // zero ms (stage-2 SAME padding: pad cols + out-of-image rows stay 0)
    #pragma unroll 1
    for (int i = tid; i < MROWS * XSTR; i += 256) ms[i] = 0.f;

    // load xs zero-padded (xs col c <-> x col c-3; xs row r <-> x row q16-6+r)
    const float* xb = x + (size_t)img * PIX;
    #pragma unroll 1
    for (int idx = tid; idx < XROWS * XSTR; idx += 256) {
        int r  = idx / XSTR, c = idx - r * XSTR;
        int gr = q16 - 6 + r, gc = c - 3;
        float v = 0.f;
        if (gr >= 0 && gr < IMG && gc >= 0 && gc < IMG)
            v = xb[gr * IMG + gc];
        xs[idx] = v;
    }
    __syncthreads();

    // ---- stage 1: 22 ms-rows x 16 col-strips = 352 strips (4 px each) ----
    #pragma unroll 1
    for (int it = 0; it < 2; ++it) {
        int s = tid + it * 256;
        if (s < MROWS * 16) {
            const int row = s >> 4;           // ms row 0..21
            const int cs4 = (s & 15) * 4;     // pixel col 0..60
            const float* bp = &xs[row * XSTR + cs4];
            DECLRQ
            float s0 = 0.f, s1 = 0.f, s2 = 0.f, s3 = 0.f;
            SUMPASS(bp)
            const float mu0 = s0 / 49.0f, mu1 = s1 / 49.0f;
            const float mu2 = s2 / 49.0f, mu3 = s3 / 49.0f;
            float a0 = 0.f, a1 = 0.f, a2 = 0.f, a3 = 0.f;
            float u0, u1;
            LDR(bp + 0*XSTR) u0 = w1s[0]; FENCE
            S1ROW_E(0, LDQ(bp + 1*XSTR))
            S1ROW_O(1, LDR(bp + 2*XSTR))
            S1ROW_E(2, LDQ(bp + 3*XSTR))
            S1ROW_O(3, LDR(bp + 4*XSTR))
            S1ROW_E(4, LDQ(bp + 5*XSTR))
            S1ROW_O(5, LDR(bp + 6*XSTR))
            S1ROW_E(6, NOPF)
            const int gm = q16 - 3 + row;
            const bool in_img = (gm >= 0) && (gm < IMG);
            float* mp = &ms[row * XSTR + 3 + cs4];
            mp[0] = in_img ? a0 : 0.f;
            mp[1] = in_img ? a1 : 0.f;
            mp[2] = in_img ? a2 : 0.f;
            mp[3] = in_img ? a3 : 0.f;
        }
    }
    __syncthreads();

    // ---- stage 2 + code bits: 16 rows x 16 col-strips = 256 strips ----
    {
        const int rr  = tid >> 4;             // out row 0..15
        const int cs4 = (tid & 15) * 4;       // pixel col 0..60
        const float* bp = &ms[rr * XSTR + cs4];
        DECLRQ
        float s0 = 0.f, s1 = 0.f, s2 = 0.f, s3 = 0.f;
        SUMPASS(bp)
        const float mu0 = s0 / 49.0f, mu1 = s1 / 49.0f;
        const float mu2 = s2 / 49.0f, mu3 = s3 / 49.0f;
        float a0=0.f,a1=0.f,a2=0.f,a3=0.f,a4=0.f,a5=0.f,a6=0.f,a7=0.f;
        float b0=0.f,b1=0.f,b2=0.f,b3=0.f,b4=0.f,b5=0.f,b6=0.f,b7=0.f;
        float c0=0.f,c1=0.f,c2=0.f,c3=0.f,c4=0.f,c5=0.f,c6=0.f,c7=0.f;
        float d0=0.f,d1=0.f,d2=0.f,d3=0.f,d4=0.f,d5=0.f,d6=0.f,d7=0.f;
        float4 wA0, wB0, wA1, wB1;
        LDR(bp + 0*XSTR) PF2(0, 0) FENCE
        S2ROW_E(0, LDQ(bp + 1*XSTR))
        S2ROW_O(1, LDR(bp + 2*XSTR))
        S2ROW_E(2, LDQ(bp + 3*XSTR))
        S2ROW_O(3, LDR(bp + 4*XSTR))
        S2ROW_E(4, LDQ(bp + 5*XSTR))
        S2ROW_O(5, LDR(bp + 6*XSTR))
        S2ROW_E(6, NOPF)
        uint32_t k0 = 0, k1 = 0, k2 = 0, k3 = 0;
        k0 |= (a0>0.f)?128u:0u; k1 |= (b0>0.f)?128u:0u; k2 |= (c0>0.f)?128u:0u; k3 |= (d0>0.f)?128u:0u;
        k0 |= (a1>0.f)? 64u:0u; k1 |= (b1>0.f)? 64u:0u; k2 |= (c1>0.f)? 64u:0u; k3 |= (d1>0.f)? 64u:0u;
        k0 |= (a2>0.f)? 32u:0u; k1 |= (b2>0.f)? 32u:0u; k2 |= (c2>0.f)? 32u:0u; k3 |= (d2>0.f)? 32u:0u;
        k0 |= (a3>0.f)? 16u:0u; k1 |= (b3>0.f)? 16u:0u; k2 |= (c3>0.f)? 16u:0u; k3 |= (d3>0.f)? 16u:0u;
        k0 |= (a4>0.f)?  8u:0u; k1 |= (b4>0.f)?  8u:0u; k2 |= (c4>0.f)?  8u:0u; k3 |= (d4>0.f)?  8u:0u;
        k0 |= (a5>0.f)?  4u:0u; k1 |= (b5>0.f)?  4u:0u; k2 |= (c5>0.f)?  4u:0u; k3 |= (d5>0.f)?  4u:0u;
        k0 |= (a6>0.f)?  2u:0u; k1 |= (b6>0.f)?  2u:0u; k2 |= (c6>0.f)?  2u:0u; k3 |= (d6>0.f)?  2u:0u;
        k0 |= (a7>0.f)?  1u:0u; k1 |= (b7>0.f)?  1u:0u; k2 |= (c7>0.f)?  1u:0u; k3 |= (d7>0.f)?  1u:0u;
        uint32_t packed = k0 | (k1 << 8) | (k2 << 16) | (k3 << 24);
        *(uint32_t*)(codes + (size_t)ch * PIX + (q16 + rr) * 64 + cs4) = packed;
    }
}

// ---------------------------------------------------------------------------
// Kernel B: histogram + entropy (unchanged, ~4 us)
// ---------------------------------------------------------------------------
#define CPB 32

__global__ __launch_bounds__(256) void hist_kernel(
    const uint8_t* __restrict__ codes,  // [512][4096]
    float* __restrict__ out)            // [49*256][512]
{
    __shared__ uint32_t hist[256 * 33];

    const int bid   = blockIdx.x;       // 0..783
    const int cgrp  = bid & 15;
    const int nb    = bid >> 4;         // 0..48
    const int bi    = nb / 7, bj = nb - bi * 7;
    const int tid   = threadIdx.x;
    const int cbase = cgrp * CPB;

    for (int i = tid; i < 256 * 33; i += 256) hist[i] = 0;
    __syncthreads();

    const int cl  = tid >> 3;           // 0..31
    const int sub = tid & 7;            // 0..7
    const uint8_t* cp = codes + (size_t)(cbase + cl) * PIX;
    #pragma unroll
    for (int rr = 0; rr < 2; ++rr) {
        int row = bi * 8 + (sub * 2 + rr);
        const uint8_t* rp = cp + row * 64 + bj * 8;
        uint64_t v0 = *(const uint64_t*)(rp);
        uint64_t v1 = *(const uint64_t*)(rp + 8);
        #pragma unroll
        for (int t = 0; t < 8; ++t)
            atomicAdd(&hist[(uint32_t)((v0 >> (8 * t)) & 255u) * 33 + cl], 1u);
        #pragma unroll
        for (int t = 0; t < 8; ++t)
            atomicAdd(&hist[(uint32_t)((v1 >> (8 * t)) & 255u) * 33 + cl], 1u);
    }
    __syncthreads();

    const int lane_c = tid & 31;
    const int bin0   = tid >> 5;        // 0..7
    for (int i = 0; i < 32; ++i) {
        int bin = i * 8 + bin0;
        uint32_t cnt = hist[bin * 33 + lane_c];
        float ent = 0.f;
        if (cnt > 0) {
            float pz = (float)cnt * (1.0f / 256.0f);
            ent = -pz * log2f(pz);
        }
        out[((size_t)(nb * 256 + bin)) * 512 + cbase + lane_c] = ent;
    }
}

extern "C" void kernel_launch(void* const* d_in, const int* in_sizes, int n_in,
                              void* d_out, int out_size, void* d_ws, size_t ws_size,
                              hipStream_t stream) {
    const float* x  = (const float*)d_in[0];
    const float* W1 = (const float*)d_in[1];
    const float* W2 = (const float*)d_in[2];
    float* out = (float*)d_out;
    uint8_t* codes = (uint8_t*)d_ws;   // 512*4096 = 2 MB

    stage_kernel<<<2048, 256, 0, stream>>>(x, W1, W2, codes);
    hist_kernel<<<784, 256, 0, stream>>>(codes, out);
}